// Round 1
// baseline (327.105 us; speedup 1.0000x reference)
//
#include <hip/hip_runtime.h>
#include <hip/hip_bf16.h>

#define N_TOKENS 16384
#define DIM      2048
#define NEXP     64
#define TOPK     8

// ---------------------------------------------------------------------------
// Kernel 1: router GEMM  logits[t][e] = sum_k hidden[t][k] * weight[e][k]
// fp32 (index stability requires fp32 logits). 64x64 tile per 256-thread
// block, BK=32, 4x4 register micro-tile per thread. K is split across
// blockIdx.y (partial logits summed in kernel 2) to double block count.
// ---------------------------------------------------------------------------
__global__ __launch_bounds__(256) void gemm_kernel(const float* __restrict__ A,
                                                   const float* __restrict__ W,
                                                   float* __restrict__ out,
                                                   int k_len) {
    __shared__ float As[32][68];   // [k][token], pad 68 to break bank conflicts
    __shared__ float Bs[32][68];   // [k][expert]

    const int tid = threadIdx.x;
    const int r = tid >> 4;        // 0..15 token group
    const int c = tid & 15;        // 0..15 expert group
    const int token_base = blockIdx.x * 64;
    const int k_start = blockIdx.y * k_len;
    out += (size_t)blockIdx.y * N_TOKENS * NEXP;

    float acc[4][4] = {};

    for (int k0 = k_start; k0 < k_start + k_len; k0 += 32) {
        // stage A(64 tok x 32 k) and W(64 exp x 32 k), transposed into LDS
        #pragma unroll
        for (int l = 0; l < 2; ++l) {
            int t2  = tid + l * 256;          // 0..511 float4 slots
            int row = t2 >> 3;                // token / expert row 0..63
            int kq  = (t2 & 7) * 4;           // k offset 0..28
            float4 va = *(const float4*)(A + (size_t)(token_base + row) * DIM + k0 + kq);
            As[kq + 0][row] = va.x; As[kq + 1][row] = va.y;
            As[kq + 2][row] = va.z; As[kq + 3][row] = va.w;
            float4 vb = *(const float4*)(W + (size_t)row * DIM + k0 + kq);
            Bs[kq + 0][row] = vb.x; Bs[kq + 1][row] = vb.y;
            Bs[kq + 2][row] = vb.z; Bs[kq + 3][row] = vb.w;
        }
        __syncthreads();

        #pragma unroll
        for (int kk = 0; kk < 32; ++kk) {
            float4 av = *(const float4*)&As[kk][4 * r];
            float4 bv = *(const float4*)&Bs[kk][4 * c];
            float a[4] = {av.x, av.y, av.z, av.w};
            float b[4] = {bv.x, bv.y, bv.z, bv.w};
            #pragma unroll
            for (int i = 0; i < 4; ++i)
                #pragma unroll
                for (int j = 0; j < 4; ++j)
                    acc[i][j] += a[i] * b[j];
        }
        __syncthreads();
    }

    #pragma unroll
    for (int i = 0; i < 4; ++i) {
        float4 v = make_float4(acc[i][0], acc[i][1], acc[i][2], acc[i][3]);
        *(float4*)(out + (size_t)(token_base + 4 * r + i) * NEXP + 4 * c) = v;
    }
}

// ---------------------------------------------------------------------------
// Kernel 2: per-token softmax + top-8 (lax.top_k semantics: sorted desc,
// ties -> lower index) + renormalized weights + per-expert partials for aux.
// One wave per token, lane = expert. 256 blocks x 4 waves, grid-stride.
// ---------------------------------------------------------------------------
__global__ __launch_bounds__(256) void topk_kernel(const float* __restrict__ l0,
                                                   const float* __restrict__ l1,
                                                   int nsplit,
                                                   float* __restrict__ out_w,
                                                   float* __restrict__ out_i,
                                                   float* __restrict__ cnt_ws,
                                                   float* __restrict__ sp_ws) {
    const int lane   = threadIdx.x & 63;
    const int wave_g = blockIdx.x * 4 + (threadIdx.x >> 6);   // 0..1023

    float sp  = 0.f;   // sum of softmax prob for expert==lane
    float cnt = 0.f;   // #times expert==lane selected

    for (int t = wave_g; t < N_TOKENS; t += 1024) {
        float lg = l0[(size_t)t * NEXP + lane];
        if (nsplit == 2) lg += l1[(size_t)t * NEXP + lane];

        // softmax over 64 lanes
        float m = lg;
        #pragma unroll
        for (int off = 32; off; off >>= 1) m = fmaxf(m, __shfl_xor(m, off));
        float e = expf(lg - m);
        float s = e;
        #pragma unroll
        for (int off = 32; off; off >>= 1) s += __shfl_xor(s, off);
        float score = e / s;
        sp += score;

        // top-8 by repeated argmax (max value, tie -> min index)
        float sel  = score;
        float wsum = 0.f;
        float myw  = 0.f;
        int   myi  = 0;
        #pragma unroll
        for (int j = 0; j < TOPK; ++j) {
            float bv = sel;
            int   bi = lane;
            #pragma unroll
            for (int off = 32; off; off >>= 1) {
                float ov = __shfl_xor(bv, off);
                int   oi = __shfl_xor(bi, off);
                if (ov > bv || (ov == bv && oi < bi)) { bv = ov; bi = oi; }
            }
            wsum += bv;                          // same value in all lanes
            if (lane == j)  { myw = bv; myi = bi; }
            if (lane == bi) { sel = -1.0f; cnt += 1.0f; }  // scores > 0 always
        }

        if (lane < TOPK) {
            out_w[(size_t)t * TOPK + lane] = myw / wsum;
            out_i[(size_t)t * TOPK + lane] = (float)myi;
        }
    }

    atomicAdd(&sp_ws[lane], sp);
    atomicAdd(&cnt_ws[lane], cnt);
}

// ---------------------------------------------------------------------------
// Kernel 3: aux_loss = ALPHA * E * sum_e (cnt[e]/(N*K)) * (sum_prob[e]/N)
// ---------------------------------------------------------------------------
__global__ void finalize_kernel(const float* __restrict__ cnt_ws,
                                const float* __restrict__ sp_ws,
                                float* __restrict__ out_aux) {
    int lane = threadIdx.x;
    float v = (cnt_ws[lane] / (float)(N_TOKENS * TOPK)) *
              (sp_ws[lane] / (float)N_TOKENS);
    #pragma unroll
    for (int off = 32; off; off >>= 1) v += __shfl_xor(v, off);
    if (lane == 0) out_aux[0] = 0.001f * (float)NEXP * v;
}

extern "C" void kernel_launch(void* const* d_in, const int* in_sizes, int n_in,
                              void* d_out, int out_size, void* d_ws, size_t ws_size,
                              hipStream_t stream) {
    const float* A = (const float*)d_in[0];   // hidden_states (16384 x 2048)
    const float* W = (const float*)d_in[1];   // weight        (64 x 2048)
    float* out = (float*)d_out;

    const size_t logits_elems = (size_t)N_TOKENS * NEXP;
    const size_t logits_bytes = logits_elems * sizeof(float);

    // K-split 2 if workspace permits (doubles block count for occupancy)
    int nsplit = (ws_size >= 2 * logits_bytes + 512) ? 2 : 1;

    float* l0     = (float*)d_ws;
    float* l1     = l0 + logits_elems;
    float* cnt_ws = (float*)((char*)d_ws + (size_t)nsplit * logits_bytes);
    float* sp_ws  = cnt_ws + NEXP;

    hipMemsetAsync(cnt_ws, 0, 2 * NEXP * sizeof(float), stream);

    dim3 grid_gemm(N_TOKENS / 64, nsplit);
    hipLaunchKernelGGL(gemm_kernel, grid_gemm, dim3(256), 0, stream,
                       A, W, l0, DIM / nsplit);

    float* out_w = out;
    float* out_i = out + (size_t)N_TOKENS * TOPK;
    float* out_a = out + 2 * (size_t)N_TOKENS * TOPK;

    hipLaunchKernelGGL(topk_kernel, dim3(256), dim3(256), 0, stream,
                       l0, l1, nsplit, out_w, out_i, cnt_ws, sp_ws);

    hipLaunchKernelGGL(finalize_kernel, dim3(1), dim3(64), 0, stream,
                       cnt_ws, sp_ws, out_a);
}

// Round 2
// 261.518 us; speedup vs baseline: 1.2508x; 1.2508x over previous
//
#include <hip/hip_runtime.h>
#include <hip/hip_bf16.h>

#define N_TOKENS 16384
#define DIM      2048
#define NEXP     64
#define TOPK     8
#define BK       32

// ---------------------------------------------------------------------------
// Kernel 1: router GEMM, fp32 (index stability requires fp32 logits).
// Tile: 256 tokens x 64 experts per 256-thread block, 8x8 register micro-tile
// (64 B LDS read per 64 lane-FMAs -> balanced against the 128 B/cyc LDS pipe,
// vs 2x oversubscribed with the old 4x4). K split across blockIdx.y into
// slabs (partials summed in kernel 2) so grid = 64 x nslab blocks.
// ---------------------------------------------------------------------------
__global__ __launch_bounds__(256) void gemm_kernel(const float* __restrict__ A,
                                                   const float* __restrict__ W,
                                                   float* __restrict__ out,
                                                   int k_len) {
    __shared__ float As[BK][260];   // [k][token], +4 pad keeps b128 alignment
    __shared__ float Bs[BK][68];    // [k][expert]

    const int tid = threadIdx.x;
    const int r = tid >> 3;         // 0..31 token group (8 tokens)
    const int c = tid & 7;          // 0..7  expert group (8 experts)
    const int token_base = blockIdx.x * 256;
    const int k_start = blockIdx.y * k_len;
    out += (size_t)blockIdx.y * N_TOKENS * NEXP;

    float acc[8][8] = {};

    for (int k0 = k_start; k0 < k_start + k_len; k0 += BK) {
        // stage A (256 tok x 32 k) transposed: 8 float4 per thread
        #pragma unroll
        for (int l = 0; l < 8; ++l) {
            int slot = tid + l * 256;       // 0..2047
            int row  = slot >> 3;           // 0..255
            int kq   = (slot & 7) * 4;      // 0..28
            float4 v = *(const float4*)(A + (size_t)(token_base + row) * DIM + k0 + kq);
            As[kq + 0][row] = v.x; As[kq + 1][row] = v.y;
            As[kq + 2][row] = v.z; As[kq + 3][row] = v.w;
        }
        // stage W (64 exp x 32 k) transposed: 2 float4 per thread
        #pragma unroll
        for (int l = 0; l < 2; ++l) {
            int slot = tid + l * 256;       // 0..511
            int row  = slot >> 3;           // 0..63
            int kq   = (slot & 7) * 4;
            float4 v = *(const float4*)(W + (size_t)row * DIM + k0 + kq);
            Bs[kq + 0][row] = v.x; Bs[kq + 1][row] = v.y;
            Bs[kq + 2][row] = v.z; Bs[kq + 3][row] = v.w;
        }
        __syncthreads();

        #pragma unroll 8
        for (int kk = 0; kk < BK; ++kk) {
            float4 a0 = *(const float4*)&As[kk][8 * r];
            float4 a1 = *(const float4*)&As[kk][8 * r + 4];
            float4 b0 = *(const float4*)&Bs[kk][8 * c];
            float4 b1 = *(const float4*)&Bs[kk][8 * c + 4];
            float a[8] = {a0.x, a0.y, a0.z, a0.w, a1.x, a1.y, a1.z, a1.w};
            float b[8] = {b0.x, b0.y, b0.z, b0.w, b1.x, b1.y, b1.z, b1.w};
            #pragma unroll
            for (int i = 0; i < 8; ++i)
                #pragma unroll
                for (int j = 0; j < 8; ++j)
                    acc[i][j] += a[i] * b[j];
        }
        __syncthreads();
    }

    #pragma unroll
    for (int i = 0; i < 8; ++i) {
        float* orow = out + (size_t)(token_base + 8 * r + i) * NEXP + 8 * c;
        *(float4*)(orow)     = make_float4(acc[i][0], acc[i][1], acc[i][2], acc[i][3]);
        *(float4*)(orow + 4) = make_float4(acc[i][4], acc[i][5], acc[i][6], acc[i][7]);
    }
}

// ---------------------------------------------------------------------------
// Kernel 2: slab-sum + softmax + top-8 via rank selection. One wave per
// token iteration (4096 waves, 4 tokens each). rank_i = #{j: s_j>s_i or
// (s_j==s_i and j<i)} gives lax.top_k semantics (sorted desc, ties->low
// index); 64 independent shuffles pipeline instead of 48 dependent hops.
// ---------------------------------------------------------------------------
__global__ __launch_bounds__(256) void topk_kernel(const float* __restrict__ logits,
                                                   int nslab,
                                                   float* __restrict__ out_w,
                                                   float* __restrict__ out_i,
                                                   float* __restrict__ cnt_ws,
                                                   float* __restrict__ sp_ws) {
    __shared__ float s_cnt[NEXP];
    __shared__ float s_sp[NEXP];
    if (threadIdx.x < NEXP) { s_cnt[threadIdx.x] = 0.f; s_sp[threadIdx.x] = 0.f; }
    __syncthreads();

    const int lane = threadIdx.x & 63;
    const int wave = blockIdx.x * 4 + (threadIdx.x >> 6);   // 0..4095

    float sp  = 0.f;
    float cnt = 0.f;

    for (int t = wave; t < N_TOKENS; t += 4096) {
        float lg = 0.f;
        for (int s = 0; s < nslab; ++s)
            lg += logits[(size_t)s * N_TOKENS * NEXP + (size_t)t * NEXP + lane];

        // softmax over 64 lanes
        float m = lg;
        #pragma unroll
        for (int off = 32; off; off >>= 1) m = fmaxf(m, __shfl_xor(m, off));
        float e = expf(lg - m);
        float ssum = e;
        #pragma unroll
        for (int off = 32; off; off >>= 1) ssum += __shfl_xor(ssum, off);
        float score = e / ssum;
        sp += score;

        // rank of this lane's score (independent, pipelined)
        int rank = 0;
        #pragma unroll
        for (int j = 0; j < 64; ++j) {
            float sj = __shfl(score, j);
            rank += (sj > score) || (sj == score && j < lane);
        }
        bool sel = rank < TOPK;

        // sum of selected scores
        float v = sel ? score : 0.f;
        #pragma unroll
        for (int off = 32; off; off >>= 1) v += __shfl_xor(v, off);

        if (sel) {
            out_w[(size_t)t * TOPK + rank] = score / v;
            out_i[(size_t)t * TOPK + rank] = (float)lane;
            cnt += 1.f;
        }
    }

    atomicAdd(&s_sp[lane], sp);
    atomicAdd(&s_cnt[lane], cnt);
    __syncthreads();
    if (threadIdx.x < 64)       atomicAdd(&cnt_ws[threadIdx.x], s_cnt[threadIdx.x]);
    else if (threadIdx.x < 128) atomicAdd(&sp_ws[threadIdx.x - 64], s_sp[threadIdx.x - 64]);
}

// ---------------------------------------------------------------------------
// Kernel 3: aux_loss = ALPHA * E * sum_e (cnt[e]/(N*K)) * (sum_prob[e]/N)
// ---------------------------------------------------------------------------
__global__ void finalize_kernel(const float* __restrict__ cnt_ws,
                                const float* __restrict__ sp_ws,
                                float* __restrict__ out_aux) {
    int lane = threadIdx.x;
    float v = (cnt_ws[lane] / (float)(N_TOKENS * TOPK)) *
              (sp_ws[lane] / (float)N_TOKENS);
    #pragma unroll
    for (int off = 32; off; off >>= 1) v += __shfl_xor(v, off);
    if (lane == 0) out_aux[0] = 0.001f * (float)NEXP * v;
}

extern "C" void kernel_launch(void* const* d_in, const int* in_sizes, int n_in,
                              void* d_out, int out_size, void* d_ws, size_t ws_size,
                              hipStream_t stream) {
    const float* A = (const float*)d_in[0];   // hidden_states (16384 x 2048)
    const float* W = (const float*)d_in[1];   // weight        (64 x 2048)
    float* out = (float*)d_out;

    const size_t logits_elems = (size_t)N_TOKENS * NEXP;
    const size_t logits_bytes = logits_elems * sizeof(float);

    // as many K-slabs as the workspace allows (8 -> 512 gemm blocks, 2/CU)
    int nslab = 1;
    if (ws_size >= 8 * logits_bytes + 1024)      nslab = 8;
    else if (ws_size >= 4 * logits_bytes + 1024) nslab = 4;
    else if (ws_size >= 2 * logits_bytes + 1024) nslab = 2;

    float* l0     = (float*)d_ws;
    float* cnt_ws = (float*)((char*)d_ws + (size_t)nslab * logits_bytes);
    float* sp_ws  = cnt_ws + NEXP;

    hipMemsetAsync(cnt_ws, 0, 2 * NEXP * sizeof(float), stream);

    hipLaunchKernelGGL(gemm_kernel, dim3(N_TOKENS / 256, nslab), dim3(256), 0, stream,
                       A, W, l0, DIM / nslab);

    float* out_w = out;
    float* out_i = out + (size_t)N_TOKENS * TOPK;
    float* out_a = out + 2 * (size_t)N_TOKENS * TOPK;

    hipLaunchKernelGGL(topk_kernel, dim3(1024), dim3(256), 0, stream,
                       l0, nslab, out_w, out_i, cnt_ws, sp_ws);

    hipLaunchKernelGGL(finalize_kernel, dim3(1), dim3(64), 0, stream,
                       cnt_ws, sp_ws, out_a);
}